// Round 5
// baseline (1456.830 us; speedup 1.0000x reference)
//
#include <hip/hip_runtime.h>

// VQ-VAE quantizer, MI355X (gfx950). Round 5: bit-exact numpy-f32 emulation.
// Reference model: np-f32 transliteration. distances = sum(p*p,1)[:,None]
//   + sum(c*c,1) - (2*flat)@cb.T computed in f32. Since n_j < ulp(A)/2 always,
//   D_j = fl32(A - 2*M_j). argmin = first-index-min over f32 values (ties ->
//   lowest index). We must match A (np pairwise sum, AVX512 vstep=16 tree),
//   M (OpenBLAS sgemm: sequential FMA over k ascending), and p (np.einsum
//   baseline SIMD: 4 lanes, mul+add, descending 4-vector cascade, hadd hsum).
//   MFMA filters: rows with margin < TAU get full np-exact rescan.

typedef _Float16 f16;
typedef _Float16 half8 __attribute__((ext_vector_type(8)));
typedef float floatx4 __attribute__((ext_vector_type(4)));

#define ROWS   32768
#define IN_DIM 1024
#define DDIM   256
#define KEMB   4096
#define TAU    0.25f
#define RPB    16
#define RSB    8

__device__ __forceinline__ float fmul(float a, float b) { return __fmul_rn(a, b); }
__device__ __forceinline__ float fadd(float a, float b) { return __fadd_rn(a, b); }

__device__ __forceinline__ void split2(float x, f16& hi, f16& lo) {
    float h = (float)(f16)x;
    if (__builtin_fabsf(h) < 6.1035156e-5f) h = 0.0f;
    hi = (f16)h;
    lo = (f16)((x - h) * 2048.0f);
}

// np.sum(x*x) over 256 contiguous f32: pairwise split 128+128; each 128-block
// via AVX512 vstep=16: r[j][l] = x^2[16j+l] (j=0..7), j-tree
// ((r0+r1)+(r2+r3))+((r4+r5)+(r6+r7)), then _mm512_reduce_add_ps lane tree.
__device__ float np_sumsq_256(const float* __restrict__ x) {
    float blk[2];
    #pragma unroll
    for (int h = 0; h < 2; ++h) {
        const float* p = x + h * 128;
        float s[16];
        #pragma unroll
        for (int l = 0; l < 16; ++l) {
            float q0 = fmul(p[l],       p[l]);
            float q1 = fmul(p[16 + l],  p[16 + l]);
            float q2 = fmul(p[32 + l],  p[32 + l]);
            float q3 = fmul(p[48 + l],  p[48 + l]);
            float q4 = fmul(p[64 + l],  p[64 + l]);
            float q5 = fmul(p[80 + l],  p[80 + l]);
            float q6 = fmul(p[96 + l],  p[96 + l]);
            float q7 = fmul(p[112 + l], p[112 + l]);
            s[l] = fadd(fadd(fadd(q0, q1), fadd(q2, q3)),
                        fadd(fadd(q4, q5), fadd(q6, q7)));
        }
        float t1[8];
        #pragma unroll
        for (int l = 0; l < 8; ++l) t1[l] = fadd(s[l], s[l + 8]);
        float t2[4];
        #pragma unroll
        for (int l = 0; l < 4; ++l) t2[l] = fadd(t1[l], t1[l + 4]);
        blk[h] = fadd(fadd(t2[0], t2[2]), fadd(t2[1], t2[3]));
    }
    return fadd(blk[0], blk[1]);
}

// ---------------------------------------------------------------- K1: prep
__global__ __launch_bounds__(256) void vq_prep_codebook(
    const float* __restrict__ cb, f16* __restrict__ chi, f16* __restrict__ clo,
    float* __restrict__ cn3)
{
    int k = blockIdx.x;
    int d = threadIdx.x;
    float c = cb[(size_t)k * DDIM + d] * 4096.0f;
    f16 hi, lo;
    split2(c, hi, lo);
    chi[(size_t)k * DDIM + d] = hi;
    clo[(size_t)k * DDIM + d] = lo;
    float sq = c * c;
    #pragma unroll
    for (int off = 32; off > 0; off >>= 1) sq += __shfl_down(sq, off);
    __shared__ float red[4];
    if ((threadIdx.x & 63) == 0) red[threadIdx.x >> 6] = sq;
    __syncthreads();
    if (threadIdx.x == 0)
        cn3[k] = (red[0] + red[1] + red[2] + red[3]) * (1.0f / 8192.0f);
}

// ---------------------------------------------------------------- K2: proj (np.einsum emu)
// Per output element: 4 f32 lane accumulators over c; per 16-element chunk the
// cascade goes vector3 -> vector2 -> vector1 -> vector0 (numpy npyv einsum);
// products rounded separately (no FMA); horizontal = (l0+l1)+(l2+l3); + bias.
__global__ __launch_bounds__(256) void vq_proj_np(
    const float* __restrict__ feat, const float* __restrict__ Wm,
    const float* __restrict__ bias, float* __restrict__ pf)
{
    __shared__ float frow[RPB][IN_DIM];
    const int r0 = blockIdx.x * RPB;
    const int tid = threadIdx.x;
    {
        const float4* src = (const float4*)(feat + (size_t)r0 * IN_DIM);
        float4* dst = (float4*)&frow[0][0];
        for (int i = tid; i < RPB * IN_DIM / 4; i += 256) dst[i] = src[i];
    }
    __syncthreads();
    const int d = tid;
    const float4* w4p = (const float4*)(Wm + (size_t)d * IN_DIM);
    float4 a[RPB];
    #pragma unroll
    for (int r = 0; r < RPB; ++r) a[r] = (float4){0.f, 0.f, 0.f, 0.f};
    for (int i = 0; i < IN_DIM / 4; i += 4) {
        float4 w0 = w4p[i], w1 = w4p[i + 1], w2 = w4p[i + 2], w3 = w4p[i + 3];
        #pragma unroll
        for (int r = 0; r < RPB; ++r) {
            const float4* f4 = (const float4*)&frow[r][i * 4];
            float4 f0 = f4[0], f1 = f4[1], f2 = f4[2], f3 = f4[3];
            float4 acc = a[r];
            acc.x = fadd(acc.x, fmul(f3.x, w3.x)); acc.y = fadd(acc.y, fmul(f3.y, w3.y));
            acc.z = fadd(acc.z, fmul(f3.z, w3.z)); acc.w = fadd(acc.w, fmul(f3.w, w3.w));
            acc.x = fadd(acc.x, fmul(f2.x, w2.x)); acc.y = fadd(acc.y, fmul(f2.y, w2.y));
            acc.z = fadd(acc.z, fmul(f2.z, w2.z)); acc.w = fadd(acc.w, fmul(f2.w, w2.w));
            acc.x = fadd(acc.x, fmul(f1.x, w1.x)); acc.y = fadd(acc.y, fmul(f1.y, w1.y));
            acc.z = fadd(acc.z, fmul(f1.z, w1.z)); acc.w = fadd(acc.w, fmul(f1.w, w1.w));
            acc.x = fadd(acc.x, fmul(f0.x, w0.x)); acc.y = fadd(acc.y, fmul(f0.y, w0.y));
            acc.z = fadd(acc.z, fmul(f0.z, w0.z)); acc.w = fadd(acc.w, fmul(f0.w, w0.w));
            a[r] = acc;
        }
    }
    const float bv = bias[d];
    #pragma unroll
    for (int r = 0; r < RPB; ++r) {
        float h = fadd(fadd(a[r].x, a[r].y), fadd(a[r].z, a[r].w));
        pf[(size_t)(r0 + r) * DDIM + d] = fadd(h, bv);
    }
}

// ---------------------------------------------------------------- K3: MFMA argmin filter
__global__ __launch_bounds__(256) void vq_argmin(
    const float* __restrict__ pf,
    const f16* __restrict__ chi, const f16* __restrict__ clo,
    const float* __restrict__ cn3, int* __restrict__ out_idx,
    int* __restrict__ fs_cnt, int* __restrict__ fs_list)
{
    __shared__ f16 PH[64][72], PL[64][72], CH[128][72], CL[128][72];
    __shared__ float mV1[64][2], mV2[64][2];
    __shared__ int   mI1[64][2];
    const int m0 = blockIdx.x * 64;
    const int tid = threadIdx.x;
    const int lane = tid & 63;
    const int w = tid >> 6;
    const int wr = w >> 1, wc = w & 1;

    float v1[8], v2[8];
    int i1[8];
    #pragma unroll
    for (int s = 0; s < 8; ++s) { v1[s] = -__builtin_inff(); v2[s] = -__builtin_inff(); i1[s] = 0; }

    for (int nt = 0; nt < KEMB / 128; ++nt) {
        floatx4 acc1[2][4], acc2[2][4];
        #pragma unroll
        for (int mi = 0; mi < 2; ++mi)
            #pragma unroll
            for (int ni = 0; ni < 4; ++ni) {
                acc1[mi][ni] = (floatx4){0.f, 0.f, 0.f, 0.f};
                acc2[mi][ni] = (floatx4){0.f, 0.f, 0.f, 0.f};
            }

        for (int ks = 0; ks < 4; ++ks) {
            {
                int r = tid >> 2, q = (tid & 3) * 16;
                const float4* s4 = (const float4*)(pf + (size_t)(m0 + r) * DDIM + ks * 64 + q);
                f16 th[16], tl[16];
                #pragma unroll
                for (int i = 0; i < 4; ++i) {
                    float4 v = s4[i];
                    split2(v.x, th[4*i+0], tl[4*i+0]);
                    split2(v.y, th[4*i+1], tl[4*i+1]);
                    split2(v.z, th[4*i+2], tl[4*i+2]);
                    split2(v.w, th[4*i+3], tl[4*i+3]);
                }
                *(half8*)&PH[r][q]     = *(half8*)&th[0];
                *(half8*)&PH[r][q + 8] = *(half8*)&th[8];
                *(half8*)&PL[r][q]     = *(half8*)&tl[0];
                *(half8*)&PL[r][q + 8] = *(half8*)&tl[8];
            }
            {
                int c = tid >> 1, hh = (tid & 1) * 32;
                const half8* ch = (const half8*)(chi + (size_t)(nt * 128 + c) * DDIM + ks * 64 + hh);
                const half8* cl = (const half8*)(clo + (size_t)(nt * 128 + c) * DDIM + ks * 64 + hh);
                #pragma unroll
                for (int i = 0; i < 4; ++i) {
                    *(half8*)&CH[c][hh + 8 * i] = ch[i];
                    *(half8*)&CL[c][hh + 8 * i] = cl[i];
                }
            }
            __syncthreads();

            #pragma unroll
            for (int kb = 0; kb < 2; ++kb) {
                const int k8 = kb * 32 + (lane >> 4) * 8;
                const int l15 = lane & 15;
                half8 aH[2], aL[2], bH[4], bL[4];
                #pragma unroll
                for (int mi = 0; mi < 2; ++mi) {
                    int r = wr * 32 + mi * 16 + l15;
                    aH[mi] = *(half8*)&PH[r][k8];
                    aL[mi] = *(half8*)&PL[r][k8];
                }
                #pragma unroll
                for (int ni = 0; ni < 4; ++ni) {
                    int c = wc * 64 + ni * 16 + l15;
                    bH[ni] = *(half8*)&CH[c][k8];
                    bL[ni] = *(half8*)&CL[c][k8];
                }
                #pragma unroll
                for (int mi = 0; mi < 2; ++mi)
                    #pragma unroll
                    for (int ni = 0; ni < 4; ++ni) {
                        acc1[mi][ni] = __builtin_amdgcn_mfma_f32_16x16x32_f16(aH[mi], bH[ni], acc1[mi][ni], 0, 0, 0);
                        acc2[mi][ni] = __builtin_amdgcn_mfma_f32_16x16x32_f16(aH[mi], bL[ni], acc2[mi][ni], 0, 0, 0);
                        acc2[mi][ni] = __builtin_amdgcn_mfma_f32_16x16x32_f16(aL[mi], bH[ni], acc2[mi][ni], 0, 0, 0);
                    }
            }
            __syncthreads();
        }

        #pragma unroll
        for (int ni = 0; ni < 4; ++ni) {
            int col = nt * 128 + wc * 64 + ni * 16 + (lane & 15);
            float cn = cn3[col];
            #pragma unroll
            for (int mi = 0; mi < 2; ++mi)
                #pragma unroll
                for (int j = 0; j < 4; ++j) {
                    float v = acc1[mi][ni][j] + acc2[mi][ni][j] * (1.0f / 2048.0f) - cn;
                    int s = mi * 4 + j;
                    if (v > v1[s])      { v2[s] = v1[s]; v1[s] = v; i1[s] = col; }
                    else if (v > v2[s]) { v2[s] = v; }
                }
        }
    }

    #pragma unroll
    for (int s = 0; s < 8; ++s) {
        float a1 = v1[s], a2 = v2[s];
        int ai = i1[s];
        #pragma unroll
        for (int m = 1; m < 16; m <<= 1) {
            float b1 = __shfl_xor(a1, m);
            float b2 = __shfl_xor(a2, m);
            int   bi = __shfl_xor(ai, m);
            float n2 = fmaxf(fminf(a1, b1), fmaxf(a2, b2));
            if (b1 > a1 || (b1 == a1 && bi < ai)) { a1 = b1; ai = bi; }
            a2 = n2;
        }
        v1[s] = a1; v2[s] = a2; i1[s] = ai;
    }
    if ((lane & 15) == 0) {
        #pragma unroll
        for (int s = 0; s < 8; ++s) {
            int mi = s >> 2, j = s & 3;
            int rloc = wr * 32 + mi * 16 + (lane >> 4) * 4 + j;
            mV1[rloc][wc] = v1[s]; mV2[rloc][wc] = v2[s];
            mI1[rloc][wc] = i1[s];
        }
    }
    __syncthreads();
    if (tid < 64) {
        float a1 = mV1[tid][0], a2 = mV2[tid][0], b1 = mV1[tid][1], b2 = mV2[tid][1];
        int ai = mI1[tid][0], bi = mI1[tid][1];
        float n2 = fmaxf(fminf(a1, b1), fmaxf(a2, b2));
        if (b1 > a1 || (b1 == a1 && bi < ai)) { a1 = b1; ai = bi; }
        out_idx[m0 + tid] = ai;
        if (a1 - n2 < TAU) {
            int slot = atomicAdd(fs_cnt, 1);
            fs_list[slot] = m0 + tid;
        }
    }
}

// ---------------------------------------------------------------- K4: np-exact rescan
// For flagged rows: D_j = fl(A - 2*seqFMA(p, c_j)) over all 4096 candidates,
// argmin with first-index tie-break (exact numpy semantics).
__global__ __launch_bounds__(512) void vq_np_rescan(
    const float* __restrict__ pf, const float* __restrict__ cb,
    const int* __restrict__ fs_list, const int* __restrict__ fs_cnt,
    int* __restrict__ out_idx)
{
    __shared__ float prow[RSB][DDIM];       // 8 KiB
    __shared__ float ctT[DDIM][66];         // 67.6 KiB, [d][j] transposed tile
    const int tid = threadIdx.x;
    const int rr = tid >> 6, jl = tid & 63;
    int cnt = *fs_cnt;
    if (cnt > ROWS) cnt = ROWS;
    for (int base = blockIdx.x * RSB; base < cnt; base += gridDim.x * RSB) {
        const int nr = min(RSB, cnt - base);
        __syncthreads();
        for (int i = tid; i < nr * (DDIM / 4); i += 512) {
            int r = i / (DDIM / 4), q = (i % (DDIM / 4)) * 4;
            *(float4*)&prow[r][q] =
                *(const float4*)&pf[(size_t)fs_list[base + r] * DDIM + q];
        }
        __syncthreads();
        float A = 0.f;
        if (rr < nr) A = np_sumsq_256(prow[rr]);
        float bD = __builtin_inff();
        int bj = 0x7fffffff;
        for (int jt = 0; jt < KEMB / 64; ++jt) {
            __syncthreads();
            {
                int j = tid & 63, db = (tid >> 6) * 32;
                const float* src = cb + (size_t)(jt * 64 + j) * DDIM + db;
                #pragma unroll
                for (int i = 0; i < 32; i += 4) {
                    float4 v = *(const float4*)(src + i);
                    ctT[db + i + 0][j] = v.x;
                    ctT[db + i + 1][j] = v.y;
                    ctT[db + i + 2][j] = v.z;
                    ctT[db + i + 3][j] = v.w;
                }
            }
            __syncthreads();
            if (rr < nr) {
                const float* p = prow[rr];
                float acc = 0.f;
                #pragma unroll 8
                for (int d = 0; d < DDIM; ++d)
                    acc = __fmaf_rn(p[d], ctT[d][jl], acc);
                float D = fadd(A, fmul(-2.0f, acc));
                int j = jt * 64 + jl;
                if (D < bD || (D == bD && j < bj)) { bD = D; bj = j; }
            }
        }
        if (rr < nr) {
            #pragma unroll
            for (int m = 1; m < 64; m <<= 1) {
                float oD = __shfl_xor(bD, m);
                int   oj = __shfl_xor(bj, m);
                if (oD < bD || (oD == bD && oj < bj)) { bD = oD; bj = oj; }
            }
            if (jl == 0) out_idx[fs_list[base + rr]] = bj;
        }
    }
}

// ---------------------------------------------------------------- K5: gather + loss partials
__global__ __launch_bounds__(256) void vq_gather(
    const float* __restrict__ cb, const float* __restrict__ pf,
    const int* __restrict__ idx,
    float* __restrict__ out0, float* __restrict__ outIdxF,
    float* __restrict__ partials)
{
    const int tid = threadIdx.x;
    const int lane = tid & 63;
    const int w = tid >> 6;
    const int row = blockIdx.x * 4 + w;
    const int k = idx[row];

    float4 c = *(const float4*)&cb[(size_t)k * DDIM + lane * 4];
    float4 p = *(const float4*)&pf[(size_t)row * DDIM + lane * 4];
    float d0 = c.x - p.x, d1 = c.y - p.y, d2 = c.z - p.z, d3 = c.w - p.w;
    float s = d0 * d0 + d1 * d1 + d2 * d2 + d3 * d3;

    *(float4*)&out0[(size_t)row * DDIM + lane * 4] = c;
    if (lane == 0) outIdxF[row] = (float)k;

    #pragma unroll
    for (int off = 32; off > 0; off >>= 1) s += __shfl_down(s, off);
    __shared__ float red[4];
    if (lane == 0) red[w] = s;
    __syncthreads();
    if (tid == 0) partials[blockIdx.x] = red[0] + red[1] + red[2] + red[3];
}

// ---------------------------------------------------------------- K6: loss reduce
__global__ __launch_bounds__(256) void vq_loss(
    const float* __restrict__ partials, float* __restrict__ out_loss)
{
    const int tid = threadIdx.x;
    float s = 0.f;
    for (int i = tid; i < ROWS / 4; i += 256) s += partials[i];
    #pragma unroll
    for (int off = 32; off > 0; off >>= 1) s += __shfl_down(s, off);
    __shared__ float red[4];
    if ((tid & 63) == 0) red[tid >> 6] = s;
    __syncthreads();
    if (tid == 0)
        out_loss[0] = 1.25f * (red[0] + red[1] + red[2] + red[3]) / 8388608.0f;
}

// ---------------------------------------------------------------- launch
extern "C" void kernel_launch(void* const* d_in, const int* in_sizes, int n_in,
                              void* d_out, int out_size, void* d_ws, size_t ws_size,
                              hipStream_t stream) {
    const float* feat = (const float*)d_in[0];
    const float* Wm   = (const float*)d_in[1];
    const float* bias = (const float*)d_in[2];
    const float* cb   = (const float*)d_in[3];

    char* ws = (char*)d_ws;
    float* pf       = (float*)(ws);               // 32 MiB
    f16*   chi      = (f16*)(ws + 33554432);      // 2 MiB
    f16*   clo      = (f16*)(ws + 35651584);      // 2 MiB
    float* cn3      = (float*)(ws + 37748736);    // 16 KiB
    int*   idx      = (int*)(ws + 37765120);      // 128 KiB
    float* partials = (float*)(ws + 37896192);    // 32 KiB
    int*   fs_cnt   = (int*)(ws + 37928960);      // 128 B
    int*   fs_list  = (int*)(ws + 37929088);      // 128 KiB

    float* out0    = (float*)d_out;
    float* outLoss = (float*)d_out + 8388608;
    float* outIdxF = (float*)d_out + 8388609;

    hipMemsetAsync(fs_cnt, 0, 4, stream);
    vq_prep_codebook<<<KEMB, 256, 0, stream>>>(cb, chi, clo, cn3);
    vq_proj_np<<<ROWS / RPB, 256, 0, stream>>>(feat, Wm, bias, pf);
    vq_argmin<<<ROWS / 64, 256, 0, stream>>>(pf, chi, clo, cn3, idx, fs_cnt, fs_list);
    vq_np_rescan<<<256, 512, 0, stream>>>(pf, cb, fs_list, fs_cnt, idx);
    vq_gather<<<ROWS / 4, 256, 0, stream>>>(cb, pf, idx, out0, outIdxF, partials);
    vq_loss<<<1, 256, 0, stream>>>(partials, outLoss);
}

// Round 6
// 912.052 us; speedup vs baseline: 1.5973x; 1.5973x over previous
//
#include <hip/hip_runtime.h>

// VQ-VAE quantizer, MI355X (gfx950). Round 6: same bit-exact np emulation as
// round 5 (PASS), optimized:
//   - rescan: register-blocked (8 rows/thread-group), coalesced f32 cbT reads,
//     grid 512 — replaces the LDS-issue-bound version (663us -> ~40us pred.)
//   - TAU 0.25 -> 0.10 (np quant step is 0.0625 scaled; fewer flagged rows)
//   - argmin: 2-pass MFMA (drop P-lo operand; noise ~2.6e-3 << TAU-quant)
// Pipeline: prep -> proj(np einsum emu) -> argmin(filter) -> transpose ->
//           rescan(np-exact) -> gather -> loss.

typedef _Float16 f16;
typedef _Float16 half8 __attribute__((ext_vector_type(8)));
typedef float floatx4 __attribute__((ext_vector_type(4)));

#define ROWS   32768
#define IN_DIM 1024
#define DDIM   256
#define KEMB   4096
#define TAU    0.10f
#define RPB    16
#define RSB    8

__device__ __forceinline__ float fmul(float a, float b) { return __fmul_rn(a, b); }
__device__ __forceinline__ float fadd(float a, float b) { return __fadd_rn(a, b); }

__device__ __forceinline__ void split2(float x, f16& hi, f16& lo) {
    float h = (float)(f16)x;
    if (__builtin_fabsf(h) < 6.1035156e-5f) h = 0.0f;
    hi = (f16)h;
    lo = (f16)((x - h) * 2048.0f);
}

// np.sum(x*x) over 256 f32: pairwise 128+128; AVX512 vstep=16 block tree.
__device__ float np_sumsq_256(const float* __restrict__ x) {
    float blk[2];
    #pragma unroll
    for (int h = 0; h < 2; ++h) {
        const float* p = x + h * 128;
        float s[16];
        #pragma unroll
        for (int l = 0; l < 16; ++l) {
            float q0 = fmul(p[l],       p[l]);
            float q1 = fmul(p[16 + l],  p[16 + l]);
            float q2 = fmul(p[32 + l],  p[32 + l]);
            float q3 = fmul(p[48 + l],  p[48 + l]);
            float q4 = fmul(p[64 + l],  p[64 + l]);
            float q5 = fmul(p[80 + l],  p[80 + l]);
            float q6 = fmul(p[96 + l],  p[96 + l]);
            float q7 = fmul(p[112 + l], p[112 + l]);
            s[l] = fadd(fadd(fadd(q0, q1), fadd(q2, q3)),
                        fadd(fadd(q4, q5), fadd(q6, q7)));
        }
        float t1[8];
        #pragma unroll
        for (int l = 0; l < 8; ++l) t1[l] = fadd(s[l], s[l + 8]);
        float t2[4];
        #pragma unroll
        for (int l = 0; l < 4; ++l) t2[l] = fadd(t1[l], t1[l + 4]);
        blk[h] = fadd(fadd(t2[0], t2[2]), fadd(t2[1], t2[3]));
    }
    return fadd(blk[0], blk[1]);
}

// ---------------------------------------------------------------- K1: prep
__global__ __launch_bounds__(256) void vq_prep_codebook(
    const float* __restrict__ cb, f16* __restrict__ chi, f16* __restrict__ clo,
    float* __restrict__ cn3)
{
    int k = blockIdx.x;
    int d = threadIdx.x;
    float c = cb[(size_t)k * DDIM + d] * 4096.0f;
    f16 hi, lo;
    split2(c, hi, lo);
    chi[(size_t)k * DDIM + d] = hi;
    clo[(size_t)k * DDIM + d] = lo;
    float sq = c * c;
    #pragma unroll
    for (int off = 32; off > 0; off >>= 1) sq += __shfl_down(sq, off);
    __shared__ float red[4];
    if ((threadIdx.x & 63) == 0) red[threadIdx.x >> 6] = sq;
    __syncthreads();
    if (threadIdx.x == 0)
        cn3[k] = (red[0] + red[1] + red[2] + red[3]) * (1.0f / 8192.0f);
}

// ---------------------------------------------------------------- K2: proj (np.einsum emu)
__global__ __launch_bounds__(256) void vq_proj_np(
    const float* __restrict__ feat, const float* __restrict__ Wm,
    const float* __restrict__ bias, float* __restrict__ pf)
{
    __shared__ float frow[RPB][IN_DIM];
    const int r0 = blockIdx.x * RPB;
    const int tid = threadIdx.x;
    {
        const float4* src = (const float4*)(feat + (size_t)r0 * IN_DIM);
        float4* dst = (float4*)&frow[0][0];
        for (int i = tid; i < RPB * IN_DIM / 4; i += 256) dst[i] = src[i];
    }
    __syncthreads();
    const int d = tid;
    const float4* w4p = (const float4*)(Wm + (size_t)d * IN_DIM);
    float4 a[RPB];
    #pragma unroll
    for (int r = 0; r < RPB; ++r) a[r] = (float4){0.f, 0.f, 0.f, 0.f};
    for (int i = 0; i < IN_DIM / 4; i += 4) {
        float4 w0 = w4p[i], w1 = w4p[i + 1], w2 = w4p[i + 2], w3 = w4p[i + 3];
        #pragma unroll
        for (int r = 0; r < RPB; ++r) {
            const float4* f4 = (const float4*)&frow[r][i * 4];
            float4 f0 = f4[0], f1 = f4[1], f2 = f4[2], f3 = f4[3];
            float4 acc = a[r];
            acc.x = fadd(acc.x, fmul(f3.x, w3.x)); acc.y = fadd(acc.y, fmul(f3.y, w3.y));
            acc.z = fadd(acc.z, fmul(f3.z, w3.z)); acc.w = fadd(acc.w, fmul(f3.w, w3.w));
            acc.x = fadd(acc.x, fmul(f2.x, w2.x)); acc.y = fadd(acc.y, fmul(f2.y, w2.y));
            acc.z = fadd(acc.z, fmul(f2.z, w2.z)); acc.w = fadd(acc.w, fmul(f2.w, w2.w));
            acc.x = fadd(acc.x, fmul(f1.x, w1.x)); acc.y = fadd(acc.y, fmul(f1.y, w1.y));
            acc.z = fadd(acc.z, fmul(f1.z, w1.z)); acc.w = fadd(acc.w, fmul(f1.w, w1.w));
            acc.x = fadd(acc.x, fmul(f0.x, w0.x)); acc.y = fadd(acc.y, fmul(f0.y, w0.y));
            acc.z = fadd(acc.z, fmul(f0.z, w0.z)); acc.w = fadd(acc.w, fmul(f0.w, w0.w));
            a[r] = acc;
        }
    }
    const float bv = bias[d];
    #pragma unroll
    for (int r = 0; r < RPB; ++r) {
        float h = fadd(fadd(a[r].x, a[r].y), fadd(a[r].z, a[r].w));
        pf[(size_t)(r0 + r) * DDIM + d] = fadd(h, bv);
    }
}

// ---------------------------------------------------------------- K3: MFMA argmin filter (2-pass)
__global__ __launch_bounds__(256) void vq_argmin(
    const float* __restrict__ pf,
    const f16* __restrict__ chi, const f16* __restrict__ clo,
    const float* __restrict__ cn3, int* __restrict__ out_idx,
    int* __restrict__ fs_cnt, int* __restrict__ fs_list)
{
    __shared__ f16 PH[64][72], CH[128][72], CL[128][72];
    __shared__ float mV1[64][2], mV2[64][2];
    __shared__ int   mI1[64][2];
    const int m0 = blockIdx.x * 64;
    const int tid = threadIdx.x;
    const int lane = tid & 63;
    const int w = tid >> 6;
    const int wr = w >> 1, wc = w & 1;

    float v1[8], v2[8];
    int i1[8];
    #pragma unroll
    for (int s = 0; s < 8; ++s) { v1[s] = -__builtin_inff(); v2[s] = -__builtin_inff(); i1[s] = 0; }

    for (int nt = 0; nt < KEMB / 128; ++nt) {
        floatx4 acc1[2][4], acc2[2][4];
        #pragma unroll
        for (int mi = 0; mi < 2; ++mi)
            #pragma unroll
            for (int ni = 0; ni < 4; ++ni) {
                acc1[mi][ni] = (floatx4){0.f, 0.f, 0.f, 0.f};
                acc2[mi][ni] = (floatx4){0.f, 0.f, 0.f, 0.f};
            }

        for (int ks = 0; ks < 4; ++ks) {
            { // stage P [64][64] hi-only, split on the fly
                int r = tid >> 2, q = (tid & 3) * 16;
                const float4* s4 = (const float4*)(pf + (size_t)(m0 + r) * DDIM + ks * 64 + q);
                f16 th[16];
                #pragma unroll
                for (int i = 0; i < 4; ++i) {
                    float4 v = s4[i];
                    f16 dead;
                    split2(v.x, th[4*i+0], dead);
                    split2(v.y, th[4*i+1], dead);
                    split2(v.z, th[4*i+2], dead);
                    split2(v.w, th[4*i+3], dead);
                }
                *(half8*)&PH[r][q]     = *(half8*)&th[0];
                *(half8*)&PH[r][q + 8] = *(half8*)&th[8];
            }
            { // stage C [128][64]
                int c = tid >> 1, hh = (tid & 1) * 32;
                const half8* ch = (const half8*)(chi + (size_t)(nt * 128 + c) * DDIM + ks * 64 + hh);
                const half8* cl = (const half8*)(clo + (size_t)(nt * 128 + c) * DDIM + ks * 64 + hh);
                #pragma unroll
                for (int i = 0; i < 4; ++i) {
                    *(half8*)&CH[c][hh + 8 * i] = ch[i];
                    *(half8*)&CL[c][hh + 8 * i] = cl[i];
                }
            }
            __syncthreads();

            #pragma unroll
            for (int kb = 0; kb < 2; ++kb) {
                const int k8 = kb * 32 + (lane >> 4) * 8;
                const int l15 = lane & 15;
                half8 aH[2], bH[4], bL[4];
                #pragma unroll
                for (int mi = 0; mi < 2; ++mi) {
                    int r = wr * 32 + mi * 16 + l15;
                    aH[mi] = *(half8*)&PH[r][k8];
                }
                #pragma unroll
                for (int ni = 0; ni < 4; ++ni) {
                    int c = wc * 64 + ni * 16 + l15;
                    bH[ni] = *(half8*)&CH[c][k8];
                    bL[ni] = *(half8*)&CL[c][k8];
                }
                #pragma unroll
                for (int mi = 0; mi < 2; ++mi)
                    #pragma unroll
                    for (int ni = 0; ni < 4; ++ni) {
                        acc1[mi][ni] = __builtin_amdgcn_mfma_f32_16x16x32_f16(aH[mi], bH[ni], acc1[mi][ni], 0, 0, 0);
                        acc2[mi][ni] = __builtin_amdgcn_mfma_f32_16x16x32_f16(aH[mi], bL[ni], acc2[mi][ni], 0, 0, 0);
                    }
            }
            __syncthreads();
        }

        #pragma unroll
        for (int ni = 0; ni < 4; ++ni) {
            int col = nt * 128 + wc * 64 + ni * 16 + (lane & 15);
            float cn = cn3[col];
            #pragma unroll
            for (int mi = 0; mi < 2; ++mi)
                #pragma unroll
                for (int j = 0; j < 4; ++j) {
                    float v = acc1[mi][ni][j] + acc2[mi][ni][j] * (1.0f / 2048.0f) - cn;
                    int s = mi * 4 + j;
                    if (v > v1[s])      { v2[s] = v1[s]; v1[s] = v; i1[s] = col; }
                    else if (v > v2[s]) { v2[s] = v; }
                }
        }
    }

    #pragma unroll
    for (int s = 0; s < 8; ++s) {
        float a1 = v1[s], a2 = v2[s];
        int ai = i1[s];
        #pragma unroll
        for (int m = 1; m < 16; m <<= 1) {
            float b1 = __shfl_xor(a1, m);
            float b2 = __shfl_xor(a2, m);
            int   bi = __shfl_xor(ai, m);
            float n2 = fmaxf(fminf(a1, b1), fmaxf(a2, b2));
            if (b1 > a1 || (b1 == a1 && bi < ai)) { a1 = b1; ai = bi; }
            a2 = n2;
        }
        v1[s] = a1; v2[s] = a2; i1[s] = ai;
    }
    if ((lane & 15) == 0) {
        #pragma unroll
        for (int s = 0; s < 8; ++s) {
            int mi = s >> 2, j = s & 3;
            int rloc = wr * 32 + mi * 16 + (lane >> 4) * 4 + j;
            mV1[rloc][wc] = v1[s]; mV2[rloc][wc] = v2[s];
            mI1[rloc][wc] = i1[s];
        }
    }
    __syncthreads();
    if (tid < 64) {
        float a1 = mV1[tid][0], a2 = mV2[tid][0], b1 = mV1[tid][1], b2 = mV2[tid][1];
        int ai = mI1[tid][0], bi = mI1[tid][1];
        float n2 = fmaxf(fminf(a1, b1), fmaxf(a2, b2));
        if (b1 > a1 || (b1 == a1 && bi < ai)) { a1 = b1; ai = bi; }
        out_idx[m0 + tid] = ai;
        if (a1 - n2 < TAU) {
            int slot = atomicAdd(fs_cnt, 1);
            fs_list[slot] = m0 + tid;
        }
    }
}

// ---------------------------------------------------------------- K3b: cb transpose (f32)
// cb[4096][256] -> cbT[256][4096]; runs after argmin (overlays chi/clo space).
__global__ __launch_bounds__(256) void vq_transpose_cb(
    const float* __restrict__ cb, float* __restrict__ cbT)
{
    __shared__ float t[64][65];
    const int j0 = blockIdx.x * 64, d0 = blockIdx.y * 64;
    const int tid = threadIdx.x;
    for (int e = tid; e < 4096; e += 256) {
        int jr = e >> 6, dc = e & 63;
        t[jr][dc] = cb[(size_t)(j0 + jr) * DDIM + d0 + dc];
    }
    __syncthreads();
    for (int e = tid; e < 4096; e += 256) {
        int dr = e >> 6, jc = e & 63;
        cbT[(size_t)(d0 + dr) * KEMB + j0 + jc] = t[jc][dr];
    }
}

// ---------------------------------------------------------------- K4: np-exact rescan (reg-blocked)
// Thread owns 4 consecutive candidates (coalesced float4 from cbT, L2-resident)
// x 8 rows of register accumulators: 32 FMAs per cb load. Arithmetic identical
// to round 5: ascending-d fmaf chain, D = fl(A - 2*acc), ascending-j strict <.
__global__ __launch_bounds__(256) void vq_np_rescan(
    const float* __restrict__ pf, const float* __restrict__ cbT,
    const int* __restrict__ fs_list, const int* __restrict__ fs_cnt,
    int* __restrict__ out_idx)
{
    __shared__ float prow[RSB][DDIM];
    __shared__ float As[RSB];
    __shared__ float rD[RSB][4];
    __shared__ int   rJ[RSB][4];
    const int tid = threadIdx.x;
    const int lane = tid & 63;
    const int wv = tid >> 6;
    int cnt = *fs_cnt;
    if (cnt > ROWS) cnt = ROWS;

    for (int base = blockIdx.x * RSB; base < cnt; base += gridDim.x * RSB) {
        const int nr = min(RSB, cnt - base);
        __syncthreads();   // prow/As reuse guard
        for (int i = tid; i < nr * 64; i += 256) {
            int r = i >> 6, q = (i & 63) * 4;
            *(float4*)&prow[r][q] =
                *(const float4*)&pf[(size_t)fs_list[base + r] * DDIM + q];
        }
        __syncthreads();
        if (tid < nr) As[tid] = np_sumsq_256(prow[tid]);
        __syncthreads();

        float bD[RSB]; int bJ[RSB];
        #pragma unroll
        for (int r = 0; r < RSB; ++r) { bD[r] = __builtin_inff(); bJ[r] = 0x7fffffff; }

        for (int sw = 0; sw < 4; ++sw) {
            const int j0 = sw * 1024 + tid * 4;
            float4 acc[RSB];
            #pragma unroll
            for (int r = 0; r < RSB; ++r) acc[r] = (float4){0.f, 0.f, 0.f, 0.f};
            for (int d4 = 0; d4 < DDIM / 4; ++d4) {
                float4 pv[RSB];
                #pragma unroll
                for (int r = 0; r < RSB; ++r)
                    pv[r] = *(const float4*)&prow[r][d4 * 4];
                #pragma unroll
                for (int dd = 0; dd < 4; ++dd) {
                    float4 cv = *(const float4*)&cbT[(size_t)(d4 * 4 + dd) * KEMB + j0];
                    #pragma unroll
                    for (int r = 0; r < RSB; ++r) {
                        float p = (dd == 0) ? pv[r].x : (dd == 1) ? pv[r].y
                                 : (dd == 2) ? pv[r].z : pv[r].w;
                        acc[r].x = __fmaf_rn(p, cv.x, acc[r].x);
                        acc[r].y = __fmaf_rn(p, cv.y, acc[r].y);
                        acc[r].z = __fmaf_rn(p, cv.z, acc[r].z);
                        acc[r].w = __fmaf_rn(p, cv.w, acc[r].w);
                    }
                }
            }
            #pragma unroll
            for (int r = 0; r < RSB; ++r) {
                float A = As[r];
                float D0 = fadd(A, fmul(-2.0f, acc[r].x));
                float D1 = fadd(A, fmul(-2.0f, acc[r].y));
                float D2 = fadd(A, fmul(-2.0f, acc[r].z));
                float D3 = fadd(A, fmul(-2.0f, acc[r].w));
                if (D0 < bD[r]) { bD[r] = D0; bJ[r] = j0; }
                if (D1 < bD[r]) { bD[r] = D1; bJ[r] = j0 + 1; }
                if (D2 < bD[r]) { bD[r] = D2; bJ[r] = j0 + 2; }
                if (D3 < bD[r]) { bD[r] = D3; bJ[r] = j0 + 3; }
            }
        }

        #pragma unroll
        for (int r = 0; r < RSB; ++r) {
            float d_ = bD[r]; int j_ = bJ[r];
            #pragma unroll
            for (int m = 1; m < 64; m <<= 1) {
                float od = __shfl_xor(d_, m);
                int   oj = __shfl_xor(j_, m);
                if (od < d_ || (od == d_ && oj < j_)) { d_ = od; j_ = oj; }
            }
            if (lane == 0) { rD[r][wv] = d_; rJ[r][wv] = j_; }
        }
        __syncthreads();
        if (tid < nr) {
            float d_ = rD[tid][0]; int j_ = rJ[tid][0];
            #pragma unroll
            for (int q = 1; q < 4; ++q) {
                float od = rD[tid][q]; int oj = rJ[tid][q];
                if (od < d_ || (od == d_ && oj < j_)) { d_ = od; j_ = oj; }
            }
            out_idx[fs_list[base + tid]] = j_;
        }
    }
}

// ---------------------------------------------------------------- K5: gather + loss partials
__global__ __launch_bounds__(256) void vq_gather(
    const float* __restrict__ cb, const float* __restrict__ pf,
    const int* __restrict__ idx,
    float* __restrict__ out0, float* __restrict__ outIdxF,
    float* __restrict__ partials)
{
    const int tid = threadIdx.x;
    const int lane = tid & 63;
    const int w = tid >> 6;
    const int row = blockIdx.x * 4 + w;
    const int k = idx[row];

    float4 c = *(const float4*)&cb[(size_t)k * DDIM + lane * 4];
    float4 p = *(const float4*)&pf[(size_t)row * DDIM + lane * 4];
    float d0 = c.x - p.x, d1 = c.y - p.y, d2 = c.z - p.z, d3 = c.w - p.w;
    float s = d0 * d0 + d1 * d1 + d2 * d2 + d3 * d3;

    *(float4*)&out0[(size_t)row * DDIM + lane * 4] = c;
    if (lane == 0) outIdxF[row] = (float)k;

    #pragma unroll
    for (int off = 32; off > 0; off >>= 1) s += __shfl_down(s, off);
    __shared__ float red[4];
    if (lane == 0) red[w] = s;
    __syncthreads();
    if (tid == 0) partials[blockIdx.x] = red[0] + red[1] + red[2] + red[3];
}

// ---------------------------------------------------------------- K6: loss reduce
__global__ __launch_bounds__(256) void vq_loss(
    const float* __restrict__ partials, float* __restrict__ out_loss)
{
    const int tid = threadIdx.x;
    float s = 0.f;
    for (int i = tid; i < ROWS / 4; i += 256) s += partials[i];
    #pragma unroll
    for (int off = 32; off > 0; off >>= 1) s += __shfl_down(s, off);
    __shared__ float red[4];
    if ((tid & 63) == 0) red[tid >> 6] = s;
    __syncthreads();
    if (tid == 0)
        out_loss[0] = 1.25f * (red[0] + red[1] + red[2] + red[3]) / 8388608.0f;
}

// ---------------------------------------------------------------- launch
extern "C" void kernel_launch(void* const* d_in, const int* in_sizes, int n_in,
                              void* d_out, int out_size, void* d_ws, size_t ws_size,
                              hipStream_t stream) {
    const float* feat = (const float*)d_in[0];
    const float* Wm   = (const float*)d_in[1];
    const float* bias = (const float*)d_in[2];
    const float* cb   = (const float*)d_in[3];

    char* ws = (char*)d_ws;
    float* pf       = (float*)(ws);               // 32 MiB
    f16*   chi      = (f16*)(ws + 33554432);      // 2 MiB  } dead after argmin;
    f16*   clo      = (f16*)(ws + 35651584);      // 2 MiB  } cbT overlays both
    float* cbT      = (float*)(ws + 33554432);    // 4 MiB f32 [256][4096]
    float* cn3      = (float*)(ws + 37748736);    // 16 KiB
    int*   idx      = (int*)(ws + 37765120);      // 128 KiB
    float* partials = (float*)(ws + 37896192);    // 32 KiB
    int*   fs_cnt   = (int*)(ws + 37928960);      // 128 B
    int*   fs_list  = (int*)(ws + 37929088);      // 128 KiB

    float* out0    = (float*)d_out;
    float* outLoss = (float*)d_out + 8388608;
    float* outIdxF = (float*)d_out + 8388609;

    hipMemsetAsync(fs_cnt, 0, 4, stream);
    vq_prep_codebook<<<KEMB, 256, 0, stream>>>(cb, chi, clo, cn3);
    vq_proj_np<<<ROWS / RPB, 256, 0, stream>>>(feat, Wm, bias, pf);
    vq_argmin<<<ROWS / 64, 256, 0, stream>>>(pf, chi, clo, cn3, idx, fs_cnt, fs_list);
    vq_transpose_cb<<<dim3(KEMB / 64, DDIM / 64), 256, 0, stream>>>(cb, cbT);
    vq_np_rescan<<<512, 256, 0, stream>>>(pf, cbT, fs_list, fs_cnt, idx);
    vq_gather<<<ROWS / 4, 256, 0, stream>>>(cb, pf, idx, out0, outIdxF, partials);
    vq_loss<<<1, 256, 0, stream>>>(partials, outLoss);
}